// Round 7
// baseline (1801.976 us; speedup 1.0000x reference)
//
#include <hip/hip_runtime.h>

// Problem constants (fixed by setup_inputs): im0 [B,C,H,W] fp32,
// flow [B,H,W,2] fp32, out [B,C,H,W] fp32.
constexpr int B_ = 4;
constexpr int C_ = 3;
constexpr int H_ = 1024;
constexpr int W_ = 1920;
constexpr int HW_ = H_ * W_;

// Gather formulation (journal R1-R6): block owns TW x TH output tile, 3
// channels in LDS, ds_add_f32 accumulation, float4 store flush; |disp|>R
// corners go to fw_far. R7 = R6 kernels UNCHANGED + two probe kernels for
// phase ablation (results read from rocprof per-dispatch durations):
//   probe_atom_noload : synthetic flow/values, real atomic pattern, x2 reps
//   probe_mem_noatomic: real loads + mask VALU, register accum, x2 reps
// Probes write only d_ws; launched after the real kernels.
constexpr int TW = 64;
constexpr int TH = 64;
constexpr int R  = 16;
constexpr int EW = TW + 2 * R;      // 96
constexpr int EH = TH + 2 * R;      // 96
constexpr int RS = 68;              // tile row stride (words)
constexpr int PLANE = RS * TH + 4;  // 4356 words
constexpr int NTHR = 512;
constexpr int QPR = EW / 4;         // 24 quads per halo row
constexpr int NQ  = QPR * EH;       // 2304 quads

static_assert(W_ % TW == 0 && H_ % TH == 0, "exact tiling assumed");
static_assert(W_ % 4 == 0 && EW % 4 == 0, "quad alignment assumed");
static_assert((RS * 4) % 16 == 0 && (PLANE * 4) % 16 == 0, "16B-aligned rows");
static_assert(3 * PLANE * 4 <= 54613, "3 blocks/CU LDS budget");

__global__ __launch_bounds__(NTHR, 6) void fw_gather(
    const float* __restrict__ im0,
    const float2* __restrict__ flow,
    const int* __restrict__ mode_p,
    float* __restrict__ out) {
    __shared__ float tile[C_ * PLANE];

    const int tx0 = blockIdx.x * TW;
    const int ty0 = blockIdx.y * TH;
    const int b   = blockIdx.z;
    const int mode = *mode_p;                  // wave-uniform

    for (int i = threadIdx.x; i < C_ * PLANE; i += NTHR) tile[i] = 0.0f;
    __syncthreads();

    const float*  im0b  = im0  + (size_t)b * C_ * HW_;
    const float2* flowb = flow + (size_t)b * HW_;

    for (int q = threadIdx.x; q < NQ; q += NTHR) {
        const int qy = q / QPR;
        const int qxl = (q - qy * QPR) * 4;
        const int gy = ty0 - R + qy;
        const int gx = tx0 - R + qxl;
        if ((unsigned)gy >= (unsigned)H_) continue;
        if ((unsigned)gx >= (unsigned)W_) continue;

        const int src = gy * W_ + gx;
        const float4 f01 = reinterpret_cast<const float4*>(flowb)[src >> 1];
        const float4 f23 = reinterpret_cast<const float4*>(flowb)[(src >> 1) + 1];
        const float4 sA  = reinterpret_cast<const float4*>(im0b)[src >> 2];
        const float4 sB  = reinterpret_cast<const float4*>(im0b + HW_)[src >> 2];
        const float4 sC  = reinterpret_cast<const float4*>(im0b + 2 * HW_)[src >> 2];

        const float fx[4] = { f01.x, f01.z, f23.x, f23.z };
        const float fy[4] = { f01.y, f01.w, f23.y, f23.w };
        const float s0[4] = { sA.x, sA.y, sA.z, sA.w };
        const float s1[4] = { sB.x, sB.y, sB.z, sB.w };
        const float s2[4] = { sC.x, sC.y, sC.z, sC.w };

        if (mode == 1) {                       // nearest
#pragma unroll
            for (int i = 0; i < 4; ++i) {
                const int gxi = gx + i;
                const int cx = (int)rintf((float)gxi + fx[i]);
                const int cy = (int)rintf((float)gy  + fy[i]);
                const int ltx = cx - tx0, lty = cy - ty0;
                const int dx = cx - gxi, dy = cy - gy;
                if ((unsigned)ltx < (unsigned)TW && (unsigned)lty < (unsigned)TH &&
                    dx >= -R && dx <= R && dy >= -R && dy <= R) {
                    const int idx = lty * RS + ltx;
                    unsafeAtomicAdd(&tile[0 * PLANE + idx], s0[i]);
                    unsafeAtomicAdd(&tile[1 * PLANE + idx], s1[i]);
                    unsafeAtomicAdd(&tile[2 * PLANE + idx], s2[i]);
                }
            }
        } else {                               // bilinear
#pragma unroll
            for (int i = 0; i < 4; ++i) {
                const int gxi = gx + i;
                const float px = (float)gxi + fx[i];
                const float py = (float)gy  + fy[i];
                const float xf = floorf(px), yf = floorf(py);
                const int x0 = (int)xf, y0 = (int)yf;
                const float wx1 = px - xf, wy1 = py - yf;
                const float wx0 = 1.0f - wx1, wy0 = 1.0f - wy1;

                const int lx0 = x0 - tx0, ly0 = y0 - ty0;
                const int dx0 = x0 - gxi, dy0 = y0 - gy;
                const bool vx0 = ((unsigned)lx0 < (unsigned)TW) &&
                                 (dx0 >= -R) && (dx0 <= R);
                const bool vx1 = ((unsigned)(lx0 + 1) < (unsigned)TW) &&
                                 (dx0 + 1 >= -R) && (dx0 + 1 <= R);
                const bool vy0 = ((unsigned)ly0 < (unsigned)TH) &&
                                 (dy0 >= -R) && (dy0 <= R);
                const bool vy1 = ((unsigned)(ly0 + 1) < (unsigned)TH) &&
                                 (dy0 + 1 >= -R) && (dy0 + 1 <= R);
                if (!((vx0 || vx1) && (vy0 || vy1))) continue;

                const int idx00 = ly0 * RS + lx0;
                if (vy0) {
                    if (vx0) {
                        const float w = wx0 * wy0;
                        unsafeAtomicAdd(&tile[0 * PLANE + idx00], s0[i] * w);
                        unsafeAtomicAdd(&tile[1 * PLANE + idx00], s1[i] * w);
                        unsafeAtomicAdd(&tile[2 * PLANE + idx00], s2[i] * w);
                    }
                    if (vx1) {
                        const float w = wx1 * wy0;
                        unsafeAtomicAdd(&tile[0 * PLANE + idx00 + 1], s0[i] * w);
                        unsafeAtomicAdd(&tile[1 * PLANE + idx00 + 1], s1[i] * w);
                        unsafeAtomicAdd(&tile[2 * PLANE + idx00 + 1], s2[i] * w);
                    }
                }
                if (vy1) {
                    if (vx0) {
                        const float w = wx0 * wy1;
                        unsafeAtomicAdd(&tile[0 * PLANE + idx00 + RS], s0[i] * w);
                        unsafeAtomicAdd(&tile[1 * PLANE + idx00 + RS], s1[i] * w);
                        unsafeAtomicAdd(&tile[2 * PLANE + idx00 + RS], s2[i] * w);
                    }
                    if (vx1) {
                        const float w = wx1 * wy1;
                        unsafeAtomicAdd(&tile[0 * PLANE + idx00 + RS + 1], s0[i] * w);
                        unsafeAtomicAdd(&tile[1 * PLANE + idx00 + RS + 1], s1[i] * w);
                        unsafeAtomicAdd(&tile[2 * PLANE + idx00 + RS + 1], s2[i] * w);
                    }
                }
            }
        }
    }
    __syncthreads();

    for (int i = threadIdx.x; i < C_ * (TW * TH / 4); i += NTHR) {
        const int c    = i >> 10;
        const int j    = i & 1023;
        const int row  = j >> 4;
        const int col4 = j & 15;
        const float4 v = *reinterpret_cast<const float4*>(
            &tile[c * PLANE + row * RS + col4 * 4]);
        float* dst = out + ((size_t)(b * C_ + c)) * HW_ +
                     (size_t)(ty0 + row) * W_ + tx0 + col4 * 4;
        *reinterpret_cast<float4*>(dst) = v;
    }
}

// Far pass: exact complement of the gather condition (unchanged).
__global__ __launch_bounds__(256) void fw_far(
    const float* __restrict__ im0,
    const float2* __restrict__ flow,
    const int* __restrict__ mode_p,
    float* __restrict__ out) {
    const int idx = blockIdx.x * 256 + threadIdx.x;
    if (idx >= B_ * HW_) return;

    const float2 f = flow[idx];
    const float lim = (float)(R - 1);
    if (fabsf(f.x) < lim && fabsf(f.y) < lim) return;

    const int mode = *mode_p;
    const int b   = idx / HW_;
    const int rem = idx - b * HW_;
    const int gy  = rem / W_;
    const int gx  = rem - gy * W_;
    const float px = (float)gx + f.x;
    const float py = (float)gy + f.y;
    const float* im0b = im0 + (size_t)b * C_ * HW_;
    float*       outb = out + (size_t)b * C_ * HW_;
    const int src = gy * W_ + gx;

    if (mode == 1) {
        const int cx = (int)rintf(px);
        const int cy = (int)rintf(py);
        const int dx = cx - gx, dy = cy - gy;
        const bool in = (unsigned)cx < (unsigned)W_ &&
                        (unsigned)cy < (unsigned)H_;
        if (in && (dx < -R || dx > R || dy < -R || dy > R)) {
            const int dsti = cy * W_ + cx;
            unsafeAtomicAdd(outb + dsti,            im0b[src]);
            unsafeAtomicAdd(outb + HW_ + dsti,      im0b[src + HW_]);
            unsafeAtomicAdd(outb + 2 * HW_ + dsti,  im0b[src + 2 * HW_]);
        }
    } else {
        const float xf = floorf(px), yf = floorf(py);
        const int x0 = (int)xf, y0 = (int)yf;
        const float wx1 = px - xf, wy1 = py - yf;
        const float wx0 = 1.0f - wx1, wy0 = 1.0f - wy1;

        const int   cxs[4] = { x0, x0 + 1, x0,     x0 + 1 };
        const int   cys[4] = { y0, y0,     y0 + 1, y0 + 1 };
        const float cws[4] = { wx0 * wy0, wx1 * wy0, wx0 * wy1, wx1 * wy1 };

        bool m[4];
        bool any = false;
#pragma unroll
        for (int k = 0; k < 4; ++k) {
            const int dx = cxs[k] - gx, dy = cys[k] - gy;
            const bool in = (unsigned)cxs[k] < (unsigned)W_ &&
                            (unsigned)cys[k] < (unsigned)H_;
            m[k] = in && (dx < -R || dx > R || dy < -R || dy > R);
            any = any || m[k];
        }
        if (!any) return;

        const float s0 = im0b[src];
        const float s1 = im0b[src + HW_];
        const float s2 = im0b[src + 2 * HW_];
#pragma unroll
        for (int k = 0; k < 4; ++k) {
            if (m[k]) {
                const int dsti = cys[k] * W_ + cxs[k];
                const float w = cws[k];
                unsafeAtomicAdd(outb + dsti,           s0 * w);
                unsafeAtomicAdd(outb + HW_ + dsti,     s1 * w);
                unsafeAtomicAdd(outb + 2 * HW_ + dsti, s2 * w);
            }
        }
    }
}

// ---------------------------------------------------------------------------
// R7 ablation probes. Output only to d_ws (timing read from rocprof rows).
// ---------------------------------------------------------------------------
__device__ __forceinline__ unsigned hash_u(unsigned x) {
    x *= 2654435761u; x ^= x >> 13; x *= 0x9E3779B1u; x ^= x >> 16;
    return x;
}

// Probe A: real 12-site LDS-atomic pattern, synthetic flow/values (no global
// loads). 2 reps of the full quad scan.
__global__ __launch_bounds__(NTHR, 6) void probe_atom_noload(
    float* __restrict__ ws) {
    __shared__ float tile[C_ * PLANE];
    const int tx0 = blockIdx.x * TW;
    const int ty0 = blockIdx.y * TH;
    const int b   = blockIdx.z;

    for (int rep = 0; rep < 2; ++rep) {
        for (int q = threadIdx.x; q < NQ; q += NTHR) {
            const int qy = q / QPR;
            const int qxl = (q - qy * QPR) * 4;
            const int gy = ty0 - R + qy;
            const int gx = tx0 - R + qxl;
            if ((unsigned)gy >= (unsigned)H_) continue;
            if ((unsigned)gx >= (unsigned)W_) continue;

#pragma unroll
            for (int i = 0; i < 4; ++i) {
                const int gxi = gx + i;
                const unsigned u = hash_u(((unsigned)(b * H_ + gy) * W_ + gxi)
                                          ^ (rep * 0x85EBCA6Bu));
                // flow ~ uniform [-8, 8) in 1/16 steps; value in [-2, 2)
                const float fxv = (float)((int)(u & 255) - 128) * 0.0625f;
                const float fyv = (float)((int)((u >> 8) & 255) - 128) * 0.0625f;
                const float sv  = (float)((int)((u >> 16) & 255) - 128) * 0.015625f;

                const float px = (float)gxi + fxv;
                const float py = (float)gy  + fyv;
                const float xf = floorf(px), yf = floorf(py);
                const int x0 = (int)xf, y0 = (int)yf;
                const float wx1 = px - xf, wy1 = py - yf;
                const float wx0 = 1.0f - wx1, wy0 = 1.0f - wy1;

                const int lx0 = x0 - tx0, ly0 = y0 - ty0;
                const int dx0 = x0 - gxi, dy0 = y0 - gy;
                const bool vx0 = ((unsigned)lx0 < (unsigned)TW) &&
                                 (dx0 >= -R) && (dx0 <= R);
                const bool vx1 = ((unsigned)(lx0 + 1) < (unsigned)TW) &&
                                 (dx0 + 1 >= -R) && (dx0 + 1 <= R);
                const bool vy0 = ((unsigned)ly0 < (unsigned)TH) &&
                                 (dy0 >= -R) && (dy0 <= R);
                const bool vy1 = ((unsigned)(ly0 + 1) < (unsigned)TH) &&
                                 (dy0 + 1 >= -R) && (dy0 + 1 <= R);
                if (!((vx0 || vx1) && (vy0 || vy1))) continue;

                const int idx00 = ly0 * RS + lx0;
                if (vy0) {
                    if (vx0) {
                        const float w = wx0 * wy0;
                        unsafeAtomicAdd(&tile[0 * PLANE + idx00], sv * w);
                        unsafeAtomicAdd(&tile[1 * PLANE + idx00], sv * w * 0.5f);
                        unsafeAtomicAdd(&tile[2 * PLANE + idx00], sv * w * 0.25f);
                    }
                    if (vx1) {
                        const float w = wx1 * wy0;
                        unsafeAtomicAdd(&tile[0 * PLANE + idx00 + 1], sv * w);
                        unsafeAtomicAdd(&tile[1 * PLANE + idx00 + 1], sv * w * 0.5f);
                        unsafeAtomicAdd(&tile[2 * PLANE + idx00 + 1], sv * w * 0.25f);
                    }
                }
                if (vy1) {
                    if (vx0) {
                        const float w = wx0 * wy1;
                        unsafeAtomicAdd(&tile[0 * PLANE + idx00 + RS], sv * w);
                        unsafeAtomicAdd(&tile[1 * PLANE + idx00 + RS], sv * w * 0.5f);
                        unsafeAtomicAdd(&tile[2 * PLANE + idx00 + RS], sv * w * 0.25f);
                    }
                    if (vx1) {
                        const float w = wx1 * wy1;
                        unsafeAtomicAdd(&tile[0 * PLANE + idx00 + RS + 1], sv * w);
                        unsafeAtomicAdd(&tile[1 * PLANE + idx00 + RS + 1], sv * w * 0.5f);
                        unsafeAtomicAdd(&tile[2 * PLANE + idx00 + RS + 1], sv * w * 0.25f);
                    }
                }
            }
        }
        __syncthreads();
    }
    if (threadIdx.x == 0) {
        const int bid = blockIdx.x + 30 * (blockIdx.y + 16 * blockIdx.z);
        ws[bid] = tile[0] + tile[1 * PLANE] + tile[2 * PLANE];
    }
}

// Probe B: real loads + full mask VALU, register accumulation (no atomics).
// Same LDS footprint for occupancy parity. 2 reps.
__global__ __launch_bounds__(NTHR, 6) void probe_mem_noatomic(
    const float* __restrict__ im0,
    const float2* __restrict__ flow,
    float* __restrict__ ws) {
    __shared__ float tile[C_ * PLANE];
    const int tx0 = blockIdx.x * TW;
    const int ty0 = blockIdx.y * TH;
    const int b   = blockIdx.z;
    const float*  im0b  = im0  + (size_t)b * C_ * HW_;
    const float2* flowb = flow + (size_t)b * HW_;

    float acc = 0.0f;
    for (int rep = 0; rep < 2; ++rep) {
        for (int q = threadIdx.x; q < NQ; q += NTHR) {
            const int qy = q / QPR;
            const int qxl = (q - qy * QPR) * 4;
            const int gy = ty0 - R + qy;
            const int gx = tx0 - R + qxl;
            if ((unsigned)gy >= (unsigned)H_) continue;
            if ((unsigned)gx >= (unsigned)W_) continue;

            const int src = gy * W_ + gx;
            const float4 f01 = reinterpret_cast<const float4*>(flowb)[src >> 1];
            const float4 f23 = reinterpret_cast<const float4*>(flowb)[(src >> 1) + 1];
            const float4 sA  = reinterpret_cast<const float4*>(im0b)[src >> 2];
            const float4 sB  = reinterpret_cast<const float4*>(im0b + HW_)[src >> 2];
            const float4 sC  = reinterpret_cast<const float4*>(im0b + 2 * HW_)[src >> 2];

            const float fx[4] = { f01.x, f01.z, f23.x, f23.z };
            const float fy[4] = { f01.y, f01.w, f23.y, f23.w };
            const float s0[4] = { sA.x, sA.y, sA.z, sA.w };
            const float s1[4] = { sB.x, sB.y, sB.z, sB.w };
            const float s2[4] = { sC.x, sC.y, sC.z, sC.w };

#pragma unroll
            for (int i = 0; i < 4; ++i) {
                const int gxi = gx + i;
                const float px = (float)gxi + fx[i];
                const float py = (float)gy  + fy[i];
                const float xf = floorf(px), yf = floorf(py);
                const int x0 = (int)xf, y0 = (int)yf;
                const float wx1 = px - xf, wy1 = py - yf;
                const float wx0 = 1.0f - wx1, wy0 = 1.0f - wy1;

                const int lx0 = x0 - tx0, ly0 = y0 - ty0;
                const int dx0 = x0 - gxi, dy0 = y0 - gy;
                const bool vx0 = ((unsigned)lx0 < (unsigned)TW) &&
                                 (dx0 >= -R) && (dx0 <= R);
                const bool vx1 = ((unsigned)(lx0 + 1) < (unsigned)TW) &&
                                 (dx0 + 1 >= -R) && (dx0 + 1 <= R);
                const bool vy0 = ((unsigned)ly0 < (unsigned)TH) &&
                                 (dy0 >= -R) && (dy0 <= R);
                const bool vy1 = ((unsigned)(ly0 + 1) < (unsigned)TH) &&
                                 (dy0 + 1 >= -R) && (dy0 + 1 <= R);
                if (!((vx0 || vx1) && (vy0 || vy1))) continue;

                if (vy0) {
                    if (vx0) { const float w = wx0 * wy0;
                        acc += s0[i] * w; acc += s1[i] * w; acc += s2[i] * w; }
                    if (vx1) { const float w = wx1 * wy0;
                        acc += s0[i] * w; acc += s1[i] * w; acc += s2[i] * w; }
                }
                if (vy1) {
                    if (vx0) { const float w = wx0 * wy1;
                        acc += s0[i] * w; acc += s1[i] * w; acc += s2[i] * w; }
                    if (vx1) { const float w = wx1 * wy1;
                        acc += s0[i] * w; acc += s1[i] * w; acc += s2[i] * w; }
                }
            }
        }
    }
    // wave reduce + per-block sum via LDS (no atomics)
#pragma unroll
    for (int off = 32; off > 0; off >>= 1) acc += __shfl_down(acc, off, 64);
    if ((threadIdx.x & 63) == 0) tile[threadIdx.x >> 6] = acc;
    __syncthreads();
    if (threadIdx.x == 0) {
        float s = 0.0f;
        for (int w = 0; w < NTHR / 64; ++w) s += tile[w];
        const int bid = blockIdx.x + 30 * (blockIdx.y + 16 * blockIdx.z);
        ws[bid] = s;
    }
}

extern "C" void kernel_launch(void* const* d_in, const int* in_sizes, int n_in,
                              void* d_out, int out_size, void* d_ws, size_t ws_size,
                              hipStream_t stream) {
    const float*  im0  = (const float*)d_in[0];
    const float2* flow = (const float2*)d_in[1];
    const int*    mode = (const int*)d_in[3];
    float* out = (float*)d_out;

    dim3 grid(W_ / TW, H_ / TH, B_);
    fw_gather<<<grid, dim3(NTHR), 0, stream>>>(im0, flow, mode, out);

    constexpr int total = B_ * HW_;
    fw_far<<<dim3((total + 255) / 256), dim3(256), 0, stream>>>(im0, flow, mode, out);

    // Ablation probes (R7 instrumentation; removed next round). Only touch
    // d_ws; timing read from rocprof per-dispatch rows.
    if (ws_size >= 1920 * sizeof(float)) {
        float* ws = (float*)d_ws;
        probe_atom_noload<<<grid, dim3(NTHR), 0, stream>>>(ws);
        probe_mem_noatomic<<<grid, dim3(NTHR), 0, stream>>>(im0, flow, ws);
    }
}